// Round 3
// baseline (6468.404 us; speedup 1.0000x reference)
//
#include <hip/hip_runtime.h>
#include <hip/hip_bf16.h>
#include <math.h>

// ---------------------------------------------------------------------------
// MultiScaleWindowGridTransformer: B=8, C=256, H=W=128, WS=8, NH=8, HD=32
// Dual-mode (bf16 / f32 input storage) self-healing pipeline with per-stage
// NaN sentinels. flags[0]=1 iff inputs detected as f32. flags[1..12] = NaN
// found after stage s. Encode kernel overwrites output with a decodable code
// on failure; otherwise output is the real result.
// ---------------------------------------------------------------------------

#define M_TOK 131072
#define CC 256
#define HH 128
#define WW 128
#define HWSZ 16384

static __device__ __forceinline__ float bf2f(unsigned short u) {
    union { float f; unsigned int i; } x; x.i = ((unsigned int)u) << 16; return x.f;
}
static __device__ __forceinline__ unsigned short f2bf(float f) {
    union { float f; unsigned int i; } x; x.f = f;
    unsigned int r = x.i + 0x7FFFu + ((x.i >> 16) & 1u);   // RNE
    return (unsigned short)(r >> 16);
}
template<int FMT> static __device__ __forceinline__ float ldin(const void* p, size_t i) {
    if (FMT == 0) return bf2f(((const unsigned short*)p)[i]);
    return ((const float*)p)[i];
}
template<int FMT> static __device__ __forceinline__ void ld4in(const void* p, size_t i, float o[4]) {
    if (FMT == 0) {
        ushort4 v = *(const ushort4*)((const unsigned short*)p + i);
        o[0] = bf2f(v.x); o[1] = bf2f(v.y); o[2] = bf2f(v.z); o[3] = bf2f(v.w);
    } else {
        float4 v = *(const float4*)((const float*)p + i);
        o[0] = v.x; o[1] = v.y; o[2] = v.z; o[3] = v.w;
    }
}

// --------------------------- diagnostics ----------------------------------
__global__ void zero_flags_kernel(int* flags) {
    if (threadIdx.x < 16) flags[threadIdx.x] = 0;
}
// max bf16-exponent-field over first 65536 u16 of x; >200 => storage is f32
__global__ void probe_kernel(const unsigned short* x, int* flags) {
    __shared__ int mx[256];
    int m = 0;
    for (int i = threadIdx.x; i < 65536; i += 256) {
        int e = (x[i] >> 7) & 0xFF;
        m = m > e ? m : e;
    }
    mx[threadIdx.x] = m; __syncthreads();
    for (int s = 128; s > 0; s >>= 1) {
        if (threadIdx.x < s) mx[threadIdx.x] = mx[threadIdx.x] > mx[threadIdx.x + s] ? mx[threadIdx.x] : mx[threadIdx.x + s];
        __syncthreads();
    }
    if (threadIdx.x == 0 && mx[0] > 200) flags[0] = 1;
}
__global__ void check_b16_kernel(const unsigned short* b, long long n, int* flags, int idx) {
    long long i = (long long)blockIdx.x * blockDim.x + threadIdx.x;
    const long long st = (long long)gridDim.x * blockDim.x;
    int bad = 0;
    for (; i < n; i += st) if ((b[i] & 0x7F80u) == 0x7F80u) { bad = 1; break; }
    if (bad) atomicOr(&flags[idx], 1);
}
__global__ void check_f32_kernel(const float* b, long long n, int* flags, int idx) {
    long long i = (long long)blockIdx.x * blockDim.x + threadIdx.x;
    const long long st = (long long)gridDim.x * blockDim.x;
    int bad = 0;
    for (; i < n; i += st) {
        union { float f; unsigned int u; } x; x.f = b[i];
        if (((x.u >> 23) & 0xFFu) == 0xFFu) { bad = 1; break; }
    }
    if (bad) atomicOr(&flags[idx], 1);
}
template<int FMT>
__global__ void encode_kernel(void* out, long long n, const int* flags) {
    if (flags[0] != FMT) return;
    float code = 0.f;
#pragma unroll
    for (int s = 12; s >= 1; --s) if (flags[s]) code = (FMT ? 49152.f : 32768.f) + 512.f * s;
    if (code == 0.f) return;
    long long i = (long long)blockIdx.x * blockDim.x + threadIdx.x;
    const long long st = (long long)gridDim.x * blockDim.x;
    for (; i < n; i += st) {
        if (FMT) ((float*)out)[i] = code;
        else ((unsigned short*)out)[i] = f2bf(code);
    }
}
__global__ void report_ws_kernel(unsigned short* out, long long n, float code) {
    long long i = (long long)blockIdx.x * blockDim.x + threadIdx.x;
    const long long st = (long long)gridDim.x * blockDim.x;
    unsigned short c = f2bf(code);
    for (; i < n; i += st) out[i] = c;
}

// --------------------------- pipeline kernels ------------------------------
// Transpose in: x [nb][C][HW] (FMT storage) -> xs [nb][HW][C] f32
template<int FMT>
__global__ __launch_bounds__(256) void transpose_in_kernel(
    const void* __restrict__ in, float* __restrict__ out, const int* __restrict__ flags)
{
    if (flags[0] != FMT) return;
    __shared__ float tile[64][65];
    const int b  = blockIdx.z;
    const int s0 = blockIdx.x * 64;
    const int r0 = blockIdx.y * 64;
    const int tx = threadIdx.x & 63;
    const int ty = threadIdx.x >> 6;
    const size_t sb = (size_t)b * CC * HWSZ;
    float* dst = out + (size_t)b * HWSZ * CC;
#pragma unroll
    for (int rr = 0; rr < 16; ++rr) {
        int row = ty + rr * 4;
        tile[row][tx] = ldin<FMT>(in, sb + (size_t)(r0 + row) * HWSZ + s0 + tx);
    }
    __syncthreads();
#pragma unroll
    for (int rr = 0; rr < 16; ++rr) {
        int srow = ty + rr * 4;
        dst[(size_t)(s0 + srow) * CC + r0 + tx] = tile[tx][srow];
    }
}

// Transpose out: xs [nb][HW][C] f32 -> out [nb][C][HW] (FMT storage)
template<int FMT>
__global__ __launch_bounds__(256) void transpose_out_kernel(
    const float* __restrict__ in, void* __restrict__ out, const int* __restrict__ flags)
{
    if (flags[0] != FMT) return;
    __shared__ float tile[64][65];
    const int b  = blockIdx.z;
    const int h0 = blockIdx.x * 64;
    const int c0 = blockIdx.y * 64;
    const int tx = threadIdx.x & 63;
    const int ty = threadIdx.x >> 6;
    const float* src = in + (size_t)b * HWSZ * CC;
    const size_t db = (size_t)b * CC * HWSZ;
#pragma unroll
    for (int rr = 0; rr < 16; ++rr) {
        int row = ty + rr * 4;
        tile[row][tx] = src[(size_t)(h0 + row) * CC + c0 + tx];
    }
    __syncthreads();
#pragma unroll
    for (int rr = 0; rr < 16; ++rr) {
        int crow = ty + rr * 4;
        size_t di = db + (size_t)(c0 + crow) * HWSZ + h0 + tx;
        float v = tile[tx][crow];
        if (FMT) ((float*)out)[di] = v;
        else ((unsigned short*)out)[di] = f2bf(v);
    }
}

// Depthwise 3x3+5x5+7x7 -> cat channel-major [768][Mc] bf16
template<int FMT>
__global__ __launch_bounds__(256) void dwconv_cat_kernel(
    const void* __restrict__ x,
    const void* __restrict__ w1, const void* __restrict__ b1,
    const void* __restrict__ w2, const void* __restrict__ b2,
    const void* __restrict__ w3, const void* __restrict__ b3,
    unsigned short* __restrict__ cat, int Mc, const int* __restrict__ flags)
{
    if (flags[0] != FMT) return;
    __shared__ float patch[8][136];
    __shared__ float wt[83];
    const int hb = blockIdx.x;
    const int c  = blockIdx.y;
    const int b  = blockIdx.z;
    const int tid = threadIdx.x;

    if (tid < 83) {
        float v;
        if (tid < 9)       v = ldin<FMT>(w1, c * 9 + tid);
        else if (tid < 34) v = ldin<FMT>(w2, c * 25 + (tid - 9));
        else               v = ldin<FMT>(w3, c * 49 + (tid - 34));
        wt[tid] = v;
    }
    const int h0 = hb * 2;
    const size_t xb = ((size_t)b * CC + c) * HWSZ;
    for (int i = tid; i < 8 * 136; i += 256) {
        int r = i / 136, col = i % 136;
        int gh = h0 - 3 + r, gw = col - 3;
        float v = 0.f;
        if (gh >= 0 && gh < HH && gw >= 0 && gw < WW) v = ldin<FMT>(x, xb + gh * WW + gw);
        patch[r][col] = v;
    }
    __syncthreads();

    const int w  = tid & 127;
    const int dh = tid >> 7;
    const int pr = dh + 3;
    float s1 = ldin<FMT>(b1, c), s2 = ldin<FMT>(b2, c), s3 = ldin<FMT>(b3, c);
#pragma unroll
    for (int dy = -1; dy <= 1; ++dy)
#pragma unroll
        for (int dx = -1; dx <= 1; ++dx)
            s1 += patch[pr + dy][w + 3 + dx] * wt[(dy + 1) * 3 + (dx + 1)];
#pragma unroll
    for (int dy = -2; dy <= 2; ++dy)
#pragma unroll
        for (int dx = -2; dx <= 2; ++dx)
            s2 += patch[pr + dy][w + 3 + dx] * wt[9 + (dy + 2) * 5 + (dx + 2)];
#pragma unroll
    for (int dy = -3; dy <= 3; ++dy)
#pragma unroll
        for (int dx = -3; dx <= 3; ++dx)
            s3 += patch[pr + dy][w + 3 + dx] * wt[34 + (dy + 3) * 7 + (dx + 3)];

    const size_t m = (size_t)b * HWSZ + (size_t)(h0 + dh) * WW + w;
    cat[(size_t)c * Mc + m]         = f2bf(s1);
    cat[(size_t)(256 + c) * Mc + m] = f2bf(s2);
    cat[(size_t)(512 + c) * Mc + m] = f2bf(s3);
}

// GEMM: C[M,N] = A*B^T + bias. A bf16 in ws (ALAYOUT 0 row-major [M,K],
// 1 K-major [K][lda]). B/bias in FMT storage. EPI 0 bf16, 1 GELU bf16, 2 += f32.
template<int ALAYOUT, int EPI, int FMT>
__global__ __launch_bounds__(256) void gemm_kernel(
    const unsigned short* __restrict__ A, const void* __restrict__ B,
    const void* __restrict__ bias, void* __restrict__ Cout,
    int N, int K, int lda, const int* __restrict__ flags)
{
    if (flags[0] != FMT) return;
    __shared__ __align__(16) float As[16][68];
    __shared__ __align__(16) float Bs[16][68];
    const int tid = threadIdx.x;
    const int m0 = blockIdx.y * 64;
    const int n0 = blockIdx.x * 64;
    const int tx = tid & 15;
    const int ty = tid >> 4;
    float acc[4][4] = {};

    for (int k0 = 0; k0 < K; k0 += 16) {
        if (ALAYOUT == 0) {
            const int mm = tid >> 2, kk4 = (tid & 3) * 4;
            ushort4 v = *(const ushort4*)(A + (size_t)(m0 + mm) * K + k0 + kk4);
            As[kk4 + 0][mm] = bf2f(v.x);
            As[kk4 + 1][mm] = bf2f(v.y);
            As[kk4 + 2][mm] = bf2f(v.z);
            As[kk4 + 3][mm] = bf2f(v.w);
        } else {
            const int kk = tid >> 4, mm4 = (tid & 15) * 4;
            ushort4 v = *(const ushort4*)(A + (size_t)(k0 + kk) * lda + m0 + mm4);
            As[kk][mm4 + 0] = bf2f(v.x);
            As[kk][mm4 + 1] = bf2f(v.y);
            As[kk][mm4 + 2] = bf2f(v.z);
            As[kk][mm4 + 3] = bf2f(v.w);
        }
        {
            const int nn = tid >> 2, kk4 = (tid & 3) * 4;
            float o[4];
            ld4in<FMT>(B, (size_t)(n0 + nn) * K + k0 + kk4, o);
            Bs[kk4 + 0][nn] = o[0];
            Bs[kk4 + 1][nn] = o[1];
            Bs[kk4 + 2][nn] = o[2];
            Bs[kk4 + 3][nn] = o[3];
        }
        __syncthreads();
#pragma unroll
        for (int kk = 0; kk < 16; ++kk) {
            float4 a4 = *(const float4*)&As[kk][ty * 4];
            float4 b4 = *(const float4*)&Bs[kk][tx * 4];
            float ar[4] = {a4.x, a4.y, a4.z, a4.w};
            float br[4] = {b4.x, b4.y, b4.z, b4.w};
#pragma unroll
            for (int i = 0; i < 4; ++i)
#pragma unroll
                for (int j = 0; j < 4; ++j)
                    acc[i][j] += ar[i] * br[j];
        }
        __syncthreads();
    }

    float bv[4];
#pragma unroll
    for (int j = 0; j < 4; ++j) bv[j] = ldin<FMT>(bias, n0 + tx * 4 + j);

#pragma unroll
    for (int i = 0; i < 4; ++i) {
        const size_t m = (size_t)(m0 + ty * 4 + i);
#pragma unroll
        for (int j = 0; j < 4; ++j) {
            const int n = n0 + tx * 4 + j;
            float v = acc[i][j] + bv[j];
            if (EPI == 0) {
                ((unsigned short*)Cout)[m * N + n] = f2bf(v);
            } else if (EPI == 1) {
                float g = 0.5f * v * (1.0f + erff(v * 0.70710678118654752f));
                ((unsigned short*)Cout)[m * N + n] = f2bf(g);
            } else {
                ((float*)Cout)[m * N + n] += v;
            }
        }
    }
}

// LayerNorm over C=256. FIN 0: bf16 ws input; FIN 1: f32 ws input. g/b in FMT.
template<int FIN, int FMT>
__global__ __launch_bounds__(256) void ln_kernel(
    const void* __restrict__ inv, const void* __restrict__ g,
    const void* __restrict__ b, unsigned short* __restrict__ out,
    const int* __restrict__ flags)
{
    if (flags[0] != FMT) return;
    const int lane = threadIdx.x & 63;
    const int wv   = threadIdx.x >> 6;
    const size_t m = (size_t)blockIdx.x * 4 + wv;
    const int c0 = lane * 4;
    float v[4];
    if (FIN == 0) {
        ushort4 u = *(const ushort4*)((const unsigned short*)inv + m * CC + c0);
        v[0] = bf2f(u.x); v[1] = bf2f(u.y); v[2] = bf2f(u.z); v[3] = bf2f(u.w);
    } else {
        float4 f = *(const float4*)((const float*)inv + m * CC + c0);
        v[0] = f.x; v[1] = f.y; v[2] = f.z; v[3] = f.w;
    }
    float s  = v[0] + v[1] + v[2] + v[3];
    float sq = v[0]*v[0] + v[1]*v[1] + v[2]*v[2] + v[3]*v[3];
#pragma unroll
    for (int off = 32; off > 0; off >>= 1) {
        s  += __shfl_xor(s,  off);
        sq += __shfl_xor(sq, off);
    }
    const float mean = s * 0.00390625f;
    float var = sq * 0.00390625f - mean * mean;
    if (var < 0.f) var = 0.f;
    const float rs = rsqrtf(var + 1e-5f);
    ushort4 o;
    o.x = f2bf((v[0] - mean) * rs * ldin<FMT>(g, c0 + 0) + ldin<FMT>(b, c0 + 0));
    o.y = f2bf((v[1] - mean) * rs * ldin<FMT>(g, c0 + 1) + ldin<FMT>(b, c0 + 1));
    o.z = f2bf((v[2] - mean) * rs * ldin<FMT>(g, c0 + 2) + ldin<FMT>(b, c0 + 2));
    o.w = f2bf((v[3] - mean) * rs * ldin<FMT>(g, c0 + 3) + ldin<FMT>(b, c0 + 3));
    *(ushort4*)(out + m * CC + c0) = o;
}

// Windowed attention (ws-only, mode-independent of FMT).
// MODE 0 (window): reverse is true inverse. MODE 1 (grid): reference's
// _grid_reverse scrambles: token (p,q) of window (i2,j2) -> h'=j2*8+(i2>>1),
// w'=(i2&1)*64+p*8+q.
template<int MODE>
__global__ __launch_bounds__(256) void attn_kernel(
    const unsigned short* __restrict__ qkv, unsigned short* __restrict__ attn_out)
{
    __shared__ float qs[64][36];
    __shared__ float ks[64][36];
    __shared__ float vs[64][36];
    __shared__ float S[64][68];
    const int tid = threadIdx.x;
    const int wi  = blockIdx.x;
    const int b   = wi >> 8;
    const int rem = wi & 255;
    const int i2  = rem >> 4;
    const int j2  = rem & 15;

    const int t  = tid >> 2;
    const int c8 = (tid & 3) * 8;
    const int p = t >> 3, qq = t & 7;
    int h_r, w_r, h_w, w_w;
    if (MODE == 0) {
        h_r = i2 * 8 + p;  w_r = j2 * 8 + qq;
        h_w = h_r;         w_w = w_r;
    } else {
        h_r = p * 16 + i2; w_r = qq * 16 + j2;
        h_w = j2 * 8 + (i2 >> 1);
        w_w = (i2 & 1) * 64 + p * 8 + qq;
    }
    const size_t gt_r = (size_t)b * HWSZ + (size_t)h_r * WW + w_r;
    const size_t gt_w = (size_t)b * HWSZ + (size_t)h_w * WW + w_w;

    const float scale = 0.17677669529663687f;
    const int ti = tid >> 4;
    const int tj = tid & 15;

    for (int head = 0; head < 8; ++head) {
        const unsigned short* base = qkv + gt_r * 768 + head * 32 + c8;
        ushort4 qa = *(const ushort4*)(base);
        ushort4 qb = *(const ushort4*)(base + 4);
        ushort4 ka = *(const ushort4*)(base + 256);
        ushort4 kb = *(const ushort4*)(base + 260);
        ushort4 va = *(const ushort4*)(base + 512);
        ushort4 vb = *(const ushort4*)(base + 516);
        qs[t][c8 + 0] = bf2f(qa.x) * scale; qs[t][c8 + 1] = bf2f(qa.y) * scale;
        qs[t][c8 + 2] = bf2f(qa.z) * scale; qs[t][c8 + 3] = bf2f(qa.w) * scale;
        qs[t][c8 + 4] = bf2f(qb.x) * scale; qs[t][c8 + 5] = bf2f(qb.y) * scale;
        qs[t][c8 + 6] = bf2f(qb.z) * scale; qs[t][c8 + 7] = bf2f(qb.w) * scale;
        ks[t][c8 + 0] = bf2f(ka.x); ks[t][c8 + 1] = bf2f(ka.y);
        ks[t][c8 + 2] = bf2f(ka.z); ks[t][c8 + 3] = bf2f(ka.w);
        ks[t][c8 + 4] = bf2f(kb.x); ks[t][c8 + 5] = bf2f(kb.y);
        ks[t][c8 + 6] = bf2f(kb.z); ks[t][c8 + 7] = bf2f(kb.w);
        vs[t][c8 + 0] = bf2f(va.x); vs[t][c8 + 1] = bf2f(va.y);
        vs[t][c8 + 2] = bf2f(va.z); vs[t][c8 + 3] = bf2f(va.w);
        vs[t][c8 + 4] = bf2f(vb.x); vs[t][c8 + 5] = bf2f(vb.y);
        vs[t][c8 + 6] = bf2f(vb.z); vs[t][c8 + 7] = bf2f(vb.w);
        __syncthreads();

        float sr[4][4] = {};
#pragma unroll 8
        for (int c = 0; c < 32; ++c) {
            float qv[4], kv[4];
#pragma unroll
            for (int i = 0; i < 4; ++i) qv[i] = qs[ti * 4 + i][c];
#pragma unroll
            for (int j = 0; j < 4; ++j) kv[j] = ks[tj * 4 + j][c];
#pragma unroll
            for (int i = 0; i < 4; ++i)
#pragma unroll
                for (int j = 0; j < 4; ++j)
                    sr[i][j] += qv[i] * kv[j];
        }
#pragma unroll
        for (int i = 0; i < 4; ++i)
#pragma unroll
            for (int j = 0; j < 4; ++j)
                S[ti * 4 + i][tj * 4 + j] = sr[i][j];
        __syncthreads();

        if (tid < 64) {
            float mx = -1e30f;
#pragma unroll 8
            for (int j = 0; j < 64; ++j) mx = fmaxf(mx, S[tid][j]);
            float sum = 0.f;
#pragma unroll 8
            for (int j = 0; j < 64; ++j) {
                float e = expf(S[tid][j] - mx);
                S[tid][j] = e;
                sum += e;
            }
            float inv = 1.f / sum;
#pragma unroll 8
            for (int j = 0; j < 64; ++j) S[tid][j] *= inv;
        }
        __syncthreads();

        float ov[8] = {};
#pragma unroll 8
        for (int j = 0; j < 64; ++j) {
            float pv = S[t][j];
            const float4 v0 = *(const float4*)&vs[j][c8];
            const float4 v1 = *(const float4*)&vs[j][c8 + 4];
            ov[0] += pv * v0.x; ov[1] += pv * v0.y;
            ov[2] += pv * v0.z; ov[3] += pv * v0.w;
            ov[4] += pv * v1.x; ov[5] += pv * v1.y;
            ov[6] += pv * v1.z; ov[7] += pv * v1.w;
        }
        unsigned short* op = attn_out + gt_w * CC + head * 32 + c8;
        ushort4 o1, o2;
        o1.x = f2bf(ov[0]); o1.y = f2bf(ov[1]); o1.z = f2bf(ov[2]); o1.w = f2bf(ov[3]);
        o2.x = f2bf(ov[4]); o2.y = f2bf(ov[5]); o2.z = f2bf(ov[6]); o2.w = f2bf(ov[7]);
        *(ushort4*)op = o1;
        *(ushort4*)(op + 4) = o2;
        __syncthreads();
    }
}

// ---------------------------------------------------------------------------
extern "C" void kernel_launch(void* const* d_in, const int* in_sizes, int n_in,
                              void* d_out, int out_size, void* d_ws, size_t ws_size,
                              hipStream_t stream)
{
    const void* x      = d_in[0];
    const void* w1     = d_in[1];  const void* b1  = d_in[2];
    const void* w2     = d_in[3];  const void* b2  = d_in[4];
    const void* w3     = d_in[5];  const void* b3  = d_in[6];
    const void* wf     = d_in[7];  const void* bf_ = d_in[8];
    const void* gw     = d_in[9];  const void* bw  = d_in[10];
    const void* wqkv_w = d_in[11]; const void* bqkv_w = d_in[12];
    const void* wo_w   = d_in[13]; const void* bo_w   = d_in[14];
    const void* gg     = d_in[15]; const void* bg  = d_in[16];
    const void* wqkv_g = d_in[17]; const void* bqkv_g = d_in[18];
    const void* wo_g   = d_in[19]; const void* bo_g   = d_in[20];
    const void* gm     = d_in[21]; const void* bm  = d_in[22];
    const void* m1w    = d_in[23]; const void* m1b = d_in[24];
    const void* m2w    = d_in[25]; const void* m2b = d_in[26];

    const size_t MiB = 1048576ull;
    const long long nout = (long long)out_size;

    // ws too small for even nb=1? report and bail.
    if (64 * MiB + 64 > ws_size) {
        float wsMiB = (float)(ws_size / MiB);
        if (wsMiB > 8192.f) wsMiB = 8192.f;
        report_ws_kernel<<<1024, 256, 0, stream>>>((unsigned short*)d_out, nout, 1024.f + wsMiB);
        return;
    }

    int nb = 8;
    while (nb > 1 && (size_t)nb * 64 * MiB + 64 > ws_size) nb >>= 1;
    const int nchunks = 8 / nb;
    const int Mc = nb * HWSZ;

    char* ws = (char*)d_ws;
    float*          xs   = (float*)ws;
    unsigned short* regA = (unsigned short*)(ws + (size_t)nb * 16 * MiB);
    unsigned short* xmat = (unsigned short*)(ws + (size_t)nb * 48 * MiB);
    unsigned short* xln  = (unsigned short*)(ws + (size_t)nb * 56 * MiB);
    int*            flags = (int*)(ws + (size_t)nb * 64 * MiB);

    zero_flags_kernel<<<1, 64, 0, stream>>>(flags);
    probe_kernel<<<1, 256, 0, stream>>>((const unsigned short*)x, flags);

    const dim3 CK(1024);
    for (int c = 0; c < nchunks; ++c) {
        const char* xcB = (const char*)x;
        // chunk offset in ELEMENTS is the same for both dtypes; byte offset differs.
        const size_t elemOff = (size_t)c * nb * CC * HWSZ;
        const void* xc0 = (const void*)((const unsigned short*)x + elemOff);  // bf16 view
        const void* xc1 = (const void*)((const float*)x + elemOff);           // f32 view
        (void)xcB;
        void* outc0 = (void*)((unsigned short*)d_out + elemOff);
        void* outc1 = (void*)((float*)d_out + elemOff);
        unsigned short* cat  = regA;
        unsigned short* qkvb = regA;
        unsigned short* h1   = regA;
        unsigned short* xm   = xmat;
        unsigned short* attn = xmat;

        transpose_in_kernel<0><<<dim3(256, 4, nb), 256, 0, stream>>>(xc0, xs, flags);
        transpose_in_kernel<1><<<dim3(256, 4, nb), 256, 0, stream>>>(xc1, xs, flags);
        check_f32_kernel<<<CK, 256, 0, stream>>>(xs, (long long)Mc * CC, flags, 1);

        dwconv_cat_kernel<0><<<dim3(64, 256, nb), 256, 0, stream>>>(xc0, w1, b1, w2, b2, w3, b3, cat, Mc, flags);
        dwconv_cat_kernel<1><<<dim3(64, 256, nb), 256, 0, stream>>>(xc1, w1, b1, w2, b2, w3, b3, cat, Mc, flags);
        check_b16_kernel<<<CK, 256, 0, stream>>>(cat, 768LL * Mc, flags, 2);

        gemm_kernel<1, 0, 0><<<dim3(4, Mc / 64), 256, 0, stream>>>(cat, wf, bf_, xm, 256, 768, Mc, flags);
        gemm_kernel<1, 0, 1><<<dim3(4, Mc / 64), 256, 0, stream>>>(cat, wf, bf_, xm, 256, 768, Mc, flags);
        check_b16_kernel<<<CK, 256, 0, stream>>>(xm, (long long)Mc * CC, flags, 3);

        // window branch
        ln_kernel<0, 0><<<Mc / 4, 256, 0, stream>>>(xm, gw, bw, xln, flags);
        ln_kernel<0, 1><<<Mc / 4, 256, 0, stream>>>(xm, gw, bw, xln, flags);
        check_b16_kernel<<<CK, 256, 0, stream>>>(xln, (long long)Mc * CC, flags, 4);
        gemm_kernel<0, 0, 0><<<dim3(12, Mc / 64), 256, 0, stream>>>(xln, wqkv_w, bqkv_w, qkvb, 768, 256, 0, flags);
        gemm_kernel<0, 0, 1><<<dim3(12, Mc / 64), 256, 0, stream>>>(xln, wqkv_w, bqkv_w, qkvb, 768, 256, 0, flags);
        check_b16_kernel<<<CK, 256, 0, stream>>>(qkvb, 768LL * Mc, flags, 5);
        attn_kernel<0><<<nb * 256, 256, 0, stream>>>(qkvb, attn);
        check_b16_kernel<<<CK, 256, 0, stream>>>(attn, (long long)Mc * CC, flags, 6);
        gemm_kernel<0, 2, 0><<<dim3(4, Mc / 64), 256, 0, stream>>>(attn, wo_w, bo_w, xs, 256, 256, 0, flags);
        gemm_kernel<0, 2, 1><<<dim3(4, Mc / 64), 256, 0, stream>>>(attn, wo_w, bo_w, xs, 256, 256, 0, flags);
        check_f32_kernel<<<CK, 256, 0, stream>>>(xs, (long long)Mc * CC, flags, 7);

        // grid branch
        ln_kernel<1, 0><<<Mc / 4, 256, 0, stream>>>(xs, gg, bg, xln, flags);
        ln_kernel<1, 1><<<Mc / 4, 256, 0, stream>>>(xs, gg, bg, xln, flags);
        gemm_kernel<0, 0, 0><<<dim3(12, Mc / 64), 256, 0, stream>>>(xln, wqkv_g, bqkv_g, qkvb, 768, 256, 0, flags);
        gemm_kernel<0, 0, 1><<<dim3(12, Mc / 64), 256, 0, stream>>>(xln, wqkv_g, bqkv_g, qkvb, 768, 256, 0, flags);
        check_b16_kernel<<<CK, 256, 0, stream>>>(qkvb, 768LL * Mc, flags, 8);
        attn_kernel<1><<<nb * 256, 256, 0, stream>>>(qkvb, attn);
        check_b16_kernel<<<CK, 256, 0, stream>>>(attn, (long long)Mc * CC, flags, 9);
        gemm_kernel<0, 2, 0><<<dim3(4, Mc / 64), 256, 0, stream>>>(attn, wo_g, bo_g, xs, 256, 256, 0, flags);
        gemm_kernel<0, 2, 1><<<dim3(4, Mc / 64), 256, 0, stream>>>(attn, wo_g, bo_g, xs, 256, 256, 0, flags);
        check_f32_kernel<<<CK, 256, 0, stream>>>(xs, (long long)Mc * CC, flags, 10);

        // MLP
        ln_kernel<1, 0><<<Mc / 4, 256, 0, stream>>>(xs, gm, bm, xln, flags);
        ln_kernel<1, 1><<<Mc / 4, 256, 0, stream>>>(xs, gm, bm, xln, flags);
        gemm_kernel<0, 1, 0><<<dim3(16, Mc / 64), 256, 0, stream>>>(xln, m1w, m1b, h1, 1024, 256, 0, flags);
        gemm_kernel<0, 1, 1><<<dim3(16, Mc / 64), 256, 0, stream>>>(xln, m1w, m1b, h1, 1024, 256, 0, flags);
        check_b16_kernel<<<CK, 256, 0, stream>>>(h1, 1024LL * Mc, flags, 11);
        gemm_kernel<0, 2, 0><<<dim3(4, Mc / 64), 256, 0, stream>>>(h1, m2w, m2b, xs, 256, 1024, 0, flags);
        gemm_kernel<0, 2, 1><<<dim3(4, Mc / 64), 256, 0, stream>>>(h1, m2w, m2b, xs, 256, 1024, 0, flags);
        check_f32_kernel<<<CK, 256, 0, stream>>>(xs, (long long)Mc * CC, flags, 12);

        transpose_out_kernel<0><<<dim3(256, 4, nb), 256, 0, stream>>>(xs, outc0, flags);
        transpose_out_kernel<1><<<dim3(256, 4, nb), 256, 0, stream>>>(xs, outc1, flags);
    }

    encode_kernel<0><<<1024, 256, 0, stream>>>(d_out, nout, flags);
    encode_kernel<1><<<1024, 256, 0, stream>>>(d_out, nout, flags);
}

// Round 4
// 3497.977 us; speedup vs baseline: 1.8492x; 1.8492x over previous
//
#include <hip/hip_runtime.h>
#include <hip/hip_bf16.h>
#include <math.h>

// ---------------------------------------------------------------------------
// MultiScaleWindowGridTransformer: B=8, C=256, H=W=128, WS=8, NH=8, HD=32
// Dual-mode (bf16 / f32 input storage) pipeline with per-stage NaN sentinels.
// Round 4: GEMMs moved to v_mfma_f32_16x16x32_bf16 (128x128 tiles, 4 waves).
// ---------------------------------------------------------------------------

#define M_TOK 131072
#define CC 256
#define HH 128
#define WW 128
#define HWSZ 16384

typedef __attribute__((ext_vector_type(8))) short short8v;   // 8 bf16 (4 VGPRs)
typedef __attribute__((ext_vector_type(4))) float float4v;   // MFMA C/D frag

static __device__ __forceinline__ float bf2f(unsigned short u) {
    union { float f; unsigned int i; } x; x.i = ((unsigned int)u) << 16; return x.f;
}
static __device__ __forceinline__ unsigned short f2bf(float f) {
    union { float f; unsigned int i; } x; x.f = f;
    unsigned int r = x.i + 0x7FFFu + ((x.i >> 16) & 1u);   // RNE
    return (unsigned short)(r >> 16);
}
template<int FMT> static __device__ __forceinline__ float ldin(const void* p, size_t i) {
    if (FMT == 0) return bf2f(((const unsigned short*)p)[i]);
    return ((const float*)p)[i];
}

// --------------------------- diagnostics ----------------------------------
__global__ void zero_flags_kernel(int* flags) {
    if (threadIdx.x < 16) flags[threadIdx.x] = 0;
}
__global__ void probe_kernel(const unsigned short* x, int* flags) {
    __shared__ int mx[256];
    int m = 0;
    for (int i = threadIdx.x; i < 65536; i += 256) {
        int e = (x[i] >> 7) & 0xFF;
        m = m > e ? m : e;
    }
    mx[threadIdx.x] = m; __syncthreads();
    for (int s = 128; s > 0; s >>= 1) {
        if (threadIdx.x < s) mx[threadIdx.x] = mx[threadIdx.x] > mx[threadIdx.x + s] ? mx[threadIdx.x] : mx[threadIdx.x + s];
        __syncthreads();
    }
    if (threadIdx.x == 0 && mx[0] > 200) flags[0] = 1;
}
__global__ void check_b16_kernel(const unsigned short* b, long long n, int* flags, int idx) {
    long long i = (long long)blockIdx.x * blockDim.x + threadIdx.x;
    const long long st = (long long)gridDim.x * blockDim.x;
    int bad = 0;
    for (; i < n; i += st) if ((b[i] & 0x7F80u) == 0x7F80u) { bad = 1; break; }
    if (bad) atomicOr(&flags[idx], 1);
}
__global__ void check_f32_kernel(const float* b, long long n, int* flags, int idx) {
    long long i = (long long)blockIdx.x * blockDim.x + threadIdx.x;
    const long long st = (long long)gridDim.x * blockDim.x;
    int bad = 0;
    for (; i < n; i += st) {
        union { float f; unsigned int u; } x; x.f = b[i];
        if (((x.u >> 23) & 0xFFu) == 0xFFu) { bad = 1; break; }
    }
    if (bad) atomicOr(&flags[idx], 1);
}
template<int FMT>
__global__ void encode_kernel(void* out, long long n, const int* flags) {
    if (flags[0] != FMT) return;
    float code = 0.f;
#pragma unroll
    for (int s = 12; s >= 1; --s) if (flags[s]) code = (FMT ? 49152.f : 32768.f) + 512.f * s;
    if (code == 0.f) return;
    long long i = (long long)blockIdx.x * blockDim.x + threadIdx.x;
    const long long st = (long long)gridDim.x * blockDim.x;
    for (; i < n; i += st) {
        if (FMT) ((float*)out)[i] = code;
        else ((unsigned short*)out)[i] = f2bf(code);
    }
}
__global__ void report_ws_kernel(unsigned short* out, long long n, float code) {
    long long i = (long long)blockIdx.x * blockDim.x + threadIdx.x;
    const long long st = (long long)gridDim.x * blockDim.x;
    unsigned short c = f2bf(code);
    for (; i < n; i += st) out[i] = c;
}

// --------------------------- pipeline kernels ------------------------------
template<int FMT>
__global__ __launch_bounds__(256) void transpose_in_kernel(
    const void* __restrict__ in, float* __restrict__ out, const int* __restrict__ flags)
{
    if (flags[0] != FMT) return;
    __shared__ float tile[64][65];
    const int b  = blockIdx.z;
    const int s0 = blockIdx.x * 64;
    const int r0 = blockIdx.y * 64;
    const int tx = threadIdx.x & 63;
    const int ty = threadIdx.x >> 6;
    const size_t sb = (size_t)b * CC * HWSZ;
    float* dst = out + (size_t)b * HWSZ * CC;
#pragma unroll
    for (int rr = 0; rr < 16; ++rr) {
        int row = ty + rr * 4;
        tile[row][tx] = ldin<FMT>(in, sb + (size_t)(r0 + row) * HWSZ + s0 + tx);
    }
    __syncthreads();
#pragma unroll
    for (int rr = 0; rr < 16; ++rr) {
        int srow = ty + rr * 4;
        dst[(size_t)(s0 + srow) * CC + r0 + tx] = tile[tx][srow];
    }
}

template<int FMT>
__global__ __launch_bounds__(256) void transpose_out_kernel(
    const float* __restrict__ in, void* __restrict__ out, const int* __restrict__ flags)
{
    if (flags[0] != FMT) return;
    __shared__ float tile[64][65];
    const int b  = blockIdx.z;
    const int h0 = blockIdx.x * 64;
    const int c0 = blockIdx.y * 64;
    const int tx = threadIdx.x & 63;
    const int ty = threadIdx.x >> 6;
    const float* src = in + (size_t)b * HWSZ * CC;
    const size_t db = (size_t)b * CC * HWSZ;
#pragma unroll
    for (int rr = 0; rr < 16; ++rr) {
        int row = ty + rr * 4;
        tile[row][tx] = src[(size_t)(h0 + row) * CC + c0 + tx];
    }
    __syncthreads();
#pragma unroll
    for (int rr = 0; rr < 16; ++rr) {
        int crow = ty + rr * 4;
        size_t di = db + (size_t)(c0 + crow) * HWSZ + h0 + tx;
        float v = tile[tx][crow];
        if (FMT) ((float*)out)[di] = v;
        else ((unsigned short*)out)[di] = f2bf(v);
    }
}

template<int FMT>
__global__ __launch_bounds__(256) void dwconv_cat_kernel(
    const void* __restrict__ x,
    const void* __restrict__ w1, const void* __restrict__ b1,
    const void* __restrict__ w2, const void* __restrict__ b2,
    const void* __restrict__ w3, const void* __restrict__ b3,
    unsigned short* __restrict__ cat, int Mc, const int* __restrict__ flags)
{
    if (flags[0] != FMT) return;
    __shared__ float patch[8][136];
    __shared__ float wt[83];
    const int hb = blockIdx.x;
    const int c  = blockIdx.y;
    const int b  = blockIdx.z;
    const int tid = threadIdx.x;

    if (tid < 83) {
        float v;
        if (tid < 9)       v = ldin<FMT>(w1, c * 9 + tid);
        else if (tid < 34) v = ldin<FMT>(w2, c * 25 + (tid - 9));
        else               v = ldin<FMT>(w3, c * 49 + (tid - 34));
        wt[tid] = v;
    }
    const int h0 = hb * 2;
    const size_t xb = ((size_t)b * CC + c) * HWSZ;
    for (int i = tid; i < 8 * 136; i += 256) {
        int r = i / 136, col = i % 136;
        int gh = h0 - 3 + r, gw = col - 3;
        float v = 0.f;
        if (gh >= 0 && gh < HH && gw >= 0 && gw < WW) v = ldin<FMT>(x, xb + gh * WW + gw);
        patch[r][col] = v;
    }
    __syncthreads();

    const int w  = tid & 127;
    const int dh = tid >> 7;
    const int pr = dh + 3;
    float s1 = ldin<FMT>(b1, c), s2 = ldin<FMT>(b2, c), s3 = ldin<FMT>(b3, c);
#pragma unroll
    for (int dy = -1; dy <= 1; ++dy)
#pragma unroll
        for (int dx = -1; dx <= 1; ++dx)
            s1 += patch[pr + dy][w + 3 + dx] * wt[(dy + 1) * 3 + (dx + 1)];
#pragma unroll
    for (int dy = -2; dy <= 2; ++dy)
#pragma unroll
        for (int dx = -2; dx <= 2; ++dx)
            s2 += patch[pr + dy][w + 3 + dx] * wt[9 + (dy + 2) * 5 + (dx + 2)];
#pragma unroll
    for (int dy = -3; dy <= 3; ++dy)
#pragma unroll
        for (int dx = -3; dx <= 3; ++dx)
            s3 += patch[pr + dy][w + 3 + dx] * wt[34 + (dy + 3) * 7 + (dx + 3)];

    const size_t m = (size_t)b * HWSZ + (size_t)(h0 + dh) * WW + w;
    cat[(size_t)c * Mc + m]         = f2bf(s1);
    cat[(size_t)(256 + c) * Mc + m] = f2bf(s2);
    cat[(size_t)(512 + c) * Mc + m] = f2bf(s3);
}

// ---------------------------------------------------------------------------
// MFMA GEMM: C[M,N] = A*W^T + bias, W [N][K] row-major (torch Linear).
// A bf16 (ws). ALAYOUT 0: A [M][K]; 1: A K-major [K][lda] (transpose-on-stage).
// EPI 0: bf16 store; 1: GELU->bf16; 2: += f32.
// 128x128 block tile, 4 waves (2x2), each wave 4x4 frags of 16x16x32, BK=64.
// LDS stride 72 bf16 keeps ds_read_b128 16B-aligned, 2-way conflicts only.
// Frag maps (guide-verified): A[m=lane&15][k=quad*8+j]; B same with n=lane&15;
// C/D col=lane&15, row=quad*4+reg.
// ---------------------------------------------------------------------------
template<int ALAYOUT, int EPI, int FMT>
__global__ __launch_bounds__(256) void gemm_mfma_kernel(
    const unsigned short* __restrict__ A, const void* __restrict__ Bw,
    const void* __restrict__ bias, void* __restrict__ Cout,
    int N, int K, int lda, const int* __restrict__ flags)
{
    if (flags[0] != FMT) return;
    __shared__ unsigned short As[128 * 72];
    __shared__ unsigned short Bs[128 * 72];
    const int tid  = threadIdx.x;
    const int lane = tid & 63;
    const int wv   = tid >> 6;
    const int wm   = (wv >> 1) * 64;
    const int wn   = (wv & 1) * 64;
    const int l15  = lane & 15;
    const int quad = lane >> 4;
    const int m0 = blockIdx.y * 128;
    const int n0 = blockIdx.x * 128;

    float4v acc[4][4] = {};

    for (int k0 = 0; k0 < K; k0 += 64) {
        __syncthreads();
        // ---- stage A tile -> As[m][k], 128x64
        if (ALAYOUT == 0) {
#pragma unroll
            for (int p = 0; p < 4; ++p) {
                const int r  = p * 32 + (tid >> 3);
                const int cc = (tid & 7) * 8;
                short8v v = *(const short8v*)(A + (size_t)(m0 + r) * K + k0 + cc);
                *(short8v*)&As[r * 72 + cc] = v;
            }
        } else {
#pragma unroll
            for (int p = 0; p < 4; ++p) {
                const int k  = p * 16 + (tid >> 4);
                const int mm = (tid & 15) * 8;
                const unsigned short* g = A + (size_t)(k0 + k) * lda + m0 + mm;
                ushort4 va = *(const ushort4*)g;
                ushort4 vb = *(const ushort4*)(g + 4);
                As[(mm + 0) * 72 + k] = va.x; As[(mm + 1) * 72 + k] = va.y;
                As[(mm + 2) * 72 + k] = va.z; As[(mm + 3) * 72 + k] = va.w;
                As[(mm + 4) * 72 + k] = vb.x; As[(mm + 5) * 72 + k] = vb.y;
                As[(mm + 6) * 72 + k] = vb.z; As[(mm + 7) * 72 + k] = vb.w;
            }
        }
        // ---- stage W tile -> Bs[n][k], 128x64
        if (FMT == 0) {
#pragma unroll
            for (int p = 0; p < 4; ++p) {
                const int r  = p * 32 + (tid >> 3);
                const int cc = (tid & 7) * 8;
                short8v v = *(const short8v*)((const unsigned short*)Bw + (size_t)(n0 + r) * K + k0 + cc);
                *(short8v*)&Bs[r * 72 + cc] = v;
            }
        } else {
#pragma unroll
            for (int p = 0; p < 4; ++p) {
                const int r  = p * 32 + (tid >> 3);
                const int cc = (tid & 7) * 8;
                const float* g = (const float*)Bw + (size_t)(n0 + r) * K + k0 + cc;
#pragma unroll
                for (int j = 0; j < 8; ++j) Bs[r * 72 + cc + j] = f2bf(g[j]);
            }
        }
        __syncthreads();

        // ---- 2 k-steps of 32, 16 MFMA each per wave
#pragma unroll
        for (int ks = 0; ks < 64; ks += 32) {
            short8v af[4], bf[4];
#pragma unroll
            for (int i = 0; i < 4; ++i)
                af[i] = *(const short8v*)&As[(wm + i * 16 + l15) * 72 + ks + quad * 8];
#pragma unroll
            for (int i = 0; i < 4; ++i)
                bf[i] = *(const short8v*)&Bs[(wn + i * 16 + l15) * 72 + ks + quad * 8];
#pragma unroll
            for (int mi = 0; mi < 4; ++mi)
#pragma unroll
                for (int ni = 0; ni < 4; ++ni)
                    acc[mi][ni] = __builtin_amdgcn_mfma_f32_16x16x32_bf16(
                        af[mi], bf[ni], acc[mi][ni], 0, 0, 0);
        }
    }

    // ---- epilogue
    float bv[4];
#pragma unroll
    for (int ni = 0; ni < 4; ++ni) bv[ni] = ldin<FMT>(bias, n0 + wn + ni * 16 + l15);

#pragma unroll
    for (int mi = 0; mi < 4; ++mi) {
#pragma unroll
        for (int r = 0; r < 4; ++r) {
            const size_t row = (size_t)(m0 + wm + mi * 16 + quad * 4 + r);
#pragma unroll
            for (int ni = 0; ni < 4; ++ni) {
                const int col = n0 + wn + ni * 16 + l15;
                float v = acc[mi][ni][r] + bv[ni];
                if (EPI == 0) {
                    ((unsigned short*)Cout)[row * N + col] = f2bf(v);
                } else if (EPI == 1) {
                    float g = 0.5f * v * (1.0f + erff(v * 0.70710678118654752f));
                    ((unsigned short*)Cout)[row * N + col] = f2bf(g);
                } else {
                    ((float*)Cout)[row * N + col] += v;
                }
            }
        }
    }
}

// LayerNorm over C=256. FIN 0: bf16 ws input; FIN 1: f32 ws input. g/b in FMT.
template<int FIN, int FMT>
__global__ __launch_bounds__(256) void ln_kernel(
    const void* __restrict__ inv, const void* __restrict__ g,
    const void* __restrict__ b, unsigned short* __restrict__ out,
    const int* __restrict__ flags)
{
    if (flags[0] != FMT) return;
    const int lane = threadIdx.x & 63;
    const int wv   = threadIdx.x >> 6;
    const size_t m = (size_t)blockIdx.x * 4 + wv;
    const int c0 = lane * 4;
    float v[4];
    if (FIN == 0) {
        ushort4 u = *(const ushort4*)((const unsigned short*)inv + m * CC + c0);
        v[0] = bf2f(u.x); v[1] = bf2f(u.y); v[2] = bf2f(u.z); v[3] = bf2f(u.w);
    } else {
        float4 f = *(const float4*)((const float*)inv + m * CC + c0);
        v[0] = f.x; v[1] = f.y; v[2] = f.z; v[3] = f.w;
    }
    float s  = v[0] + v[1] + v[2] + v[3];
    float sq = v[0]*v[0] + v[1]*v[1] + v[2]*v[2] + v[3]*v[3];
#pragma unroll
    for (int off = 32; off > 0; off >>= 1) {
        s  += __shfl_xor(s,  off);
        sq += __shfl_xor(sq, off);
    }
    const float mean = s * 0.00390625f;
    float var = sq * 0.00390625f - mean * mean;
    if (var < 0.f) var = 0.f;
    const float rs = rsqrtf(var + 1e-5f);
    ushort4 o;
    o.x = f2bf((v[0] - mean) * rs * ldin<FMT>(g, c0 + 0) + ldin<FMT>(b, c0 + 0));
    o.y = f2bf((v[1] - mean) * rs * ldin<FMT>(g, c0 + 1) + ldin<FMT>(b, c0 + 1));
    o.z = f2bf((v[2] - mean) * rs * ldin<FMT>(g, c0 + 2) + ldin<FMT>(b, c0 + 2));
    o.w = f2bf((v[3] - mean) * rs * ldin<FMT>(g, c0 + 3) + ldin<FMT>(b, c0 + 3));
    *(ushort4*)(out + m * CC + c0) = o;
}

// Windowed attention. MODE 0 window (reverse = inverse); MODE 1 grid:
// token (p,q) of window (i2,j2) scatters to h'=j2*8+(i2>>1), w'=(i2&1)*64+p*8+q.
template<int MODE>
__global__ __launch_bounds__(256) void attn_kernel(
    const unsigned short* __restrict__ qkv, unsigned short* __restrict__ attn_out)
{
    __shared__ float qs[64][36];
    __shared__ float ks[64][36];
    __shared__ float vs[64][36];
    __shared__ float S[64][68];
    const int tid = threadIdx.x;
    const int wi  = blockIdx.x;
    const int b   = wi >> 8;
    const int rem = wi & 255;
    const int i2  = rem >> 4;
    const int j2  = rem & 15;

    const int t  = tid >> 2;
    const int c8 = (tid & 3) * 8;
    const int p = t >> 3, qq = t & 7;
    int h_r, w_r, h_w, w_w;
    if (MODE == 0) {
        h_r = i2 * 8 + p;  w_r = j2 * 8 + qq;
        h_w = h_r;         w_w = w_r;
    } else {
        h_r = p * 16 + i2; w_r = qq * 16 + j2;
        h_w = j2 * 8 + (i2 >> 1);
        w_w = (i2 & 1) * 64 + p * 8 + qq;
    }
    const size_t gt_r = (size_t)b * HWSZ + (size_t)h_r * WW + w_r;
    const size_t gt_w = (size_t)b * HWSZ + (size_t)h_w * WW + w_w;

    const float scale = 0.17677669529663687f;
    const int ti = tid >> 4;
    const int tj = tid & 15;

    for (int head = 0; head < 8; ++head) {
        const unsigned short* base = qkv + gt_r * 768 + head * 32 + c8;
        ushort4 qa = *(const ushort4*)(base);
        ushort4 qb = *(const ushort4*)(base + 4);
        ushort4 ka = *(const ushort4*)(base + 256);
        ushort4 kb = *(const ushort4*)(base + 260);
        ushort4 va = *(const ushort4*)(base + 512);
        ushort4 vb = *(const ushort4*)(base + 516);
        qs[t][c8 + 0] = bf2f(qa.x) * scale; qs[t][c8 + 1] = bf2f(qa.y) * scale;
        qs[t][c8 + 2] = bf2f(qa.z) * scale; qs[t][c8 + 3] = bf2f(qa.w) * scale;
        qs[t][c8 + 4] = bf2f(qb.x) * scale; qs[t][c8 + 5] = bf2f(qb.y) * scale;
        qs[t][c8 + 6] = bf2f(qb.z) * scale; qs[t][c8 + 7] = bf2f(qb.w) * scale;
        ks[t][c8 + 0] = bf2f(ka.x); ks[t][c8 + 1] = bf2f(ka.y);
        ks[t][c8 + 2] = bf2f(ka.z); ks[t][c8 + 3] = bf2f(ka.w);
        ks[t][c8 + 4] = bf2f(kb.x); ks[t][c8 + 5] = bf2f(kb.y);
        ks[t][c8 + 6] = bf2f(kb.z); ks[t][c8 + 7] = bf2f(kb.w);
        vs[t][c8 + 0] = bf2f(va.x); vs[t][c8 + 1] = bf2f(va.y);
        vs[t][c8 + 2] = bf2f(va.z); vs[t][c8 + 3] = bf2f(va.w);
        vs[t][c8 + 4] = bf2f(vb.x); vs[t][c8 + 5] = bf2f(vb.y);
        vs[t][c8 + 6] = bf2f(vb.z); vs[t][c8 + 7] = bf2f(vb.w);
        __syncthreads();

        float sr[4][4] = {};
#pragma unroll 8
        for (int c = 0; c < 32; ++c) {
            float qv[4], kv[4];
#pragma unroll
            for (int i = 0; i < 4; ++i) qv[i] = qs[ti * 4 + i][c];
#pragma unroll
            for (int j = 0; j < 4; ++j) kv[j] = ks[tj * 4 + j][c];
#pragma unroll
            for (int i = 0; i < 4; ++i)
#pragma unroll
                for (int j = 0; j < 4; ++j)
                    sr[i][j] += qv[i] * kv[j];
        }
#pragma unroll
        for (int i = 0; i < 4; ++i)
#pragma unroll
            for (int j = 0; j < 4; ++j)
                S[ti * 4 + i][tj * 4 + j] = sr[i][j];
        __syncthreads();

        if (tid < 64) {
            float mx = -1e30f;
#pragma unroll 8
            for (int j = 0; j < 64; ++j) mx = fmaxf(mx, S[tid][j]);
            float sum = 0.f;
#pragma unroll 8
            for (int j = 0; j < 64; ++j) {
                float e = expf(S[tid][j] - mx);
                S[tid][j] = e;
                sum += e;
            }
            float inv = 1.f / sum;
#pragma unroll 8
            for (int j = 0; j < 64; ++j) S[tid][j] *= inv;
        }
        __syncthreads();

        float ov[8] = {};
#pragma unroll 8
        for (int j = 0; j < 64; ++j) {
            float pv = S[t][j];
            const float4 v0 = *(const float4*)&vs[j][c8];
            const float4 v1 = *(const float4*)&vs[j][c8 + 4];
            ov[0] += pv * v0.x; ov[1] += pv * v0.y;
            ov[2] += pv * v0.z; ov[3] += pv * v0.w;
            ov[4] += pv * v1.x; ov[5] += pv * v1.y;
            ov[6] += pv * v1.z; ov[7] += pv * v1.w;
        }
        unsigned short* op = attn_out + gt_w * CC + head * 32 + c8;
        ushort4 o1, o2;
        o1.x = f2bf(ov[0]); o1.y = f2bf(ov[1]); o1.z = f2bf(ov[2]); o1.w = f2bf(ov[3]);
        o2.x = f2bf(ov[4]); o2.y = f2bf(ov[5]); o2.z = f2bf(ov[6]); o2.w = f2bf(ov[7]);
        *(ushort4*)op = o1;
        *(ushort4*)(op + 4) = o2;
        __syncthreads();
    }
}

// ---------------------------------------------------------------------------
extern "C" void kernel_launch(void* const* d_in, const int* in_sizes, int n_in,
                              void* d_out, int out_size, void* d_ws, size_t ws_size,
                              hipStream_t stream)
{
    const void* x      = d_in[0];
    const void* w1     = d_in[1];  const void* b1  = d_in[2];
    const void* w2     = d_in[3];  const void* b2  = d_in[4];
    const void* w3     = d_in[5];  const void* b3  = d_in[6];
    const void* wf     = d_in[7];  const void* bf_ = d_in[8];
    const void* gw     = d_in[9];  const void* bw  = d_in[10];
    const void* wqkv_w = d_in[11]; const void* bqkv_w = d_in[12];
    const void* wo_w   = d_in[13]; const void* bo_w   = d_in[14];
    const void* gg     = d_in[15]; const void* bg  = d_in[16];
    const void* wqkv_g = d_in[17]; const void* bqkv_g = d_in[18];
    const void* wo_g   = d_in[19]; const void* bo_g   = d_in[20];
    const void* gm     = d_in[21]; const void* bm  = d_in[22];
    const void* m1w    = d_in[23]; const void* m1b = d_in[24];
    const void* m2w    = d_in[25]; const void* m2b = d_in[26];

    const size_t MiB = 1048576ull;
    const long long nout = (long long)out_size;

    if (64 * MiB + 64 > ws_size) {
        float wsMiB = (float)(ws_size / MiB);
        if (wsMiB > 8192.f) wsMiB = 8192.f;
        report_ws_kernel<<<1024, 256, 0, stream>>>((unsigned short*)d_out, nout, 1024.f + wsMiB);
        return;
    }

    int nb = 8;
    while (nb > 1 && (size_t)nb * 64 * MiB + 64 > ws_size) nb >>= 1;
    const int nchunks = 8 / nb;
    const int Mc = nb * HWSZ;

    char* ws = (char*)d_ws;
    float*          xs   = (float*)ws;
    unsigned short* regA = (unsigned short*)(ws + (size_t)nb * 16 * MiB);
    unsigned short* xmat = (unsigned short*)(ws + (size_t)nb * 48 * MiB);
    unsigned short* xln  = (unsigned short*)(ws + (size_t)nb * 56 * MiB);
    int*            flags = (int*)(ws + (size_t)nb * 64 * MiB);

    zero_flags_kernel<<<1, 64, 0, stream>>>(flags);
    probe_kernel<<<1, 256, 0, stream>>>((const unsigned short*)x, flags);

    const dim3 CK(1024);
    const int MB = Mc / 128;   // gemm grid y
    for (int c = 0; c < nchunks; ++c) {
        const size_t elemOff = (size_t)c * nb * CC * HWSZ;
        const void* xc0 = (const void*)((const unsigned short*)x + elemOff);
        const void* xc1 = (const void*)((const float*)x + elemOff);
        void* outc0 = (void*)((unsigned short*)d_out + elemOff);
        void* outc1 = (void*)((float*)d_out + elemOff);
        unsigned short* cat  = regA;
        unsigned short* qkvb = regA;
        unsigned short* h1   = regA;
        unsigned short* xm   = xmat;
        unsigned short* attn = xmat;

        transpose_in_kernel<0><<<dim3(256, 4, nb), 256, 0, stream>>>(xc0, xs, flags);
        transpose_in_kernel<1><<<dim3(256, 4, nb), 256, 0, stream>>>(xc1, xs, flags);
        check_f32_kernel<<<CK, 256, 0, stream>>>(xs, (long long)Mc * CC, flags, 1);

        dwconv_cat_kernel<0><<<dim3(64, 256, nb), 256, 0, stream>>>(xc0, w1, b1, w2, b2, w3, b3, cat, Mc, flags);
        dwconv_cat_kernel<1><<<dim3(64, 256, nb), 256, 0, stream>>>(xc1, w1, b1, w2, b2, w3, b3, cat, Mc, flags);
        check_b16_kernel<<<CK, 256, 0, stream>>>(cat, 768LL * Mc, flags, 2);

        gemm_mfma_kernel<1, 0, 0><<<dim3(2, MB), 256, 0, stream>>>(cat, wf, bf_, xm, 256, 768, Mc, flags);
        gemm_mfma_kernel<1, 0, 1><<<dim3(2, MB), 256, 0, stream>>>(cat, wf, bf_, xm, 256, 768, Mc, flags);
        check_b16_kernel<<<CK, 256, 0, stream>>>(xm, (long long)Mc * CC, flags, 3);

        // window branch
        ln_kernel<0, 0><<<Mc / 4, 256, 0, stream>>>(xm, gw, bw, xln, flags);
        ln_kernel<0, 1><<<Mc / 4, 256, 0, stream>>>(xm, gw, bw, xln, flags);
        check_b16_kernel<<<CK, 256, 0, stream>>>(xln, (long long)Mc * CC, flags, 4);
        gemm_mfma_kernel<0, 0, 0><<<dim3(6, MB), 256, 0, stream>>>(xln, wqkv_w, bqkv_w, qkvb, 768, 256, 0, flags);
        gemm_mfma_kernel<0, 0, 1><<<dim3(6, MB), 256, 0, stream>>>(xln, wqkv_w, bqkv_w, qkvb, 768, 256, 0, flags);
        check_b16_kernel<<<CK, 256, 0, stream>>>(qkvb, 768LL * Mc, flags, 5);
        attn_kernel<0><<<nb * 256, 256, 0, stream>>>(qkvb, attn);
        check_b16_kernel<<<CK, 256, 0, stream>>>(attn, (long long)Mc * CC, flags, 6);
        gemm_mfma_kernel<0, 2, 0><<<dim3(2, MB), 256, 0, stream>>>(attn, wo_w, bo_w, xs, 256, 256, 0, flags);
        gemm_mfma_kernel<0, 2, 1><<<dim3(2, MB), 256, 0, stream>>>(attn, wo_w, bo_w, xs, 256, 256, 0, flags);
        check_f32_kernel<<<CK, 256, 0, stream>>>(xs, (long long)Mc * CC, flags, 7);

        // grid branch
        ln_kernel<1, 0><<<Mc / 4, 256, 0, stream>>>(xs, gg, bg, xln, flags);
        ln_kernel<1, 1><<<Mc / 4, 256, 0, stream>>>(xs, gg, bg, xln, flags);
        gemm_mfma_kernel<0, 0, 0><<<dim3(6, MB), 256, 0, stream>>>(xln, wqkv_g, bqkv_g, qkvb, 768, 256, 0, flags);
        gemm_mfma_kernel<0, 0, 1><<<dim3(6, MB), 256, 0, stream>>>(xln, wqkv_g, bqkv_g, qkvb, 768, 256, 0, flags);
        check_b16_kernel<<<CK, 256, 0, stream>>>(qkvb, 768LL * Mc, flags, 8);
        attn_kernel<1><<<nb * 256, 256, 0, stream>>>(qkvb, attn);
        check_b16_kernel<<<CK, 256, 0, stream>>>(attn, (long long)Mc * CC, flags, 9);
        gemm_mfma_kernel<0, 2, 0><<<dim3(2, MB), 256, 0, stream>>>(attn, wo_g, bo_g, xs, 256, 256, 0, flags);
        gemm_mfma_kernel<0, 2, 1><<<dim3(2, MB), 256, 0, stream>>>(attn, wo_g, bo_g, xs, 256, 256, 0, flags);
        check_f32_kernel<<<CK, 256, 0, stream>>>(xs, (long long)Mc * CC, flags, 10);

        // MLP
        ln_kernel<1, 0><<<Mc / 4, 256, 0, stream>>>(xs, gm, bm, xln, flags);
        ln_kernel<1, 1><<<Mc / 4, 256, 0, stream>>>(xs, gm, bm, xln, flags);
        gemm_mfma_kernel<0, 1, 0><<<dim3(8, MB), 256, 0, stream>>>(xln, m1w, m1b, h1, 1024, 256, 0, flags);
        gemm_mfma_kernel<0, 1, 1><<<dim3(8, MB), 256, 0, stream>>>(xln, m1w, m1b, h1, 1024, 256, 0, flags);
        check_b16_kernel<<<CK, 256, 0, stream>>>(h1, 1024LL * Mc, flags, 11);
        gemm_mfma_kernel<0, 2, 0><<<dim3(2, MB), 256, 0, stream>>>(h1, m2w, m2b, xs, 256, 1024, 0, flags);
        gemm_mfma_kernel<0, 2, 1><<<dim3(2, MB), 256, 0, stream>>>(h1, m2w, m2b, xs, 256, 1024, 0, flags);
        check_f32_kernel<<<CK, 256, 0, stream>>>(xs, (long long)Mc * CC, flags, 12);

        transpose_out_kernel<0><<<dim3(256, 4, nb), 256, 0, stream>>>(xs, outc0, flags);
        transpose_out_kernel<1><<<dim3(256, 4, nb), 256, 0, stream>>>(xs, outc1, flags);
    }

    encode_kernel<0><<<1024, 256, 0, stream>>>(d_out, nout, flags);
    encode_kernel<1><<<1024, 256, 0, stream>>>(d_out, nout, flags);
}